// Round 1
// baseline (357.962 us; speedup 1.0000x reference)
//
#include <hip/hip_runtime.h>
#include <math.h>

#define NNV 4096   // N
#define KKV 64     // K
#define BBV 256    // B
#define TILE 32    // n-tile staged in LDS

// ---------------- C transpose: C[64][4096] -> Ct[4096][64] ----------------
__global__ __launch_bounds__(256) void ct_transpose(const float* __restrict__ C,
                                                    float* __restrict__ Ct) {
    __shared__ float tile[64][65];
    const int n0 = blockIdx.x * 64;
    const int t = threadIdx.x;
#pragma unroll
    for (int i = 0; i < 16; ++i) {
        int idx = i * 256 + t;
        int k = idx >> 6, nn = idx & 63;
        tile[nn][k] = C[k * NNV + n0 + nn];   // coalesced read along n
    }
    __syncthreads();
#pragma unroll
    for (int i = 0; i < 16; ++i) {
        int idx = i * 256 + t;
        int nn = idx >> 6, k = idx & 63;
        Ct[(n0 + nn) * 64 + k] = tile[nn][k]; // coalesced write along k
    }
}

// ---------------- main: one block per batch row ----------------
__global__ __launch_bounds__(256) void zif_main(const float* __restrict__ targets,
                                                const float* __restrict__ rho,
                                                const float* __restrict__ qs,
                                                const float* __restrict__ means,
                                                const float* __restrict__ Ct,
                                                const float* __restrict__ psi,
                                                float* __restrict__ out) {
    __shared__ float wbuf[NNV];     // w = m/psi
    __shared__ float wdbuf[NNV];    // w*d
    __shared__ float AC[64 * 65];   // phase2: Cs tile (stride 68); phase3: A (stride 65)
    __shared__ float colv[64];
    __shared__ float ubuf[64];
    __shared__ float sred[4 * 5];

    const int b = blockIdx.x;
    const int t = threadIdx.x;
    const int lane = t & 63;
    const int wid = t >> 6;

    const float rho_s = rho[0];
    const float lrho = __logf(rho_s);

    // ---------- phase 1: elementwise pass ----------
    float s_uni = 0.f, s_wdd = 0.f, s_nb = 0.f, s_mlp = 0.f, s_extra = 0.f;
    {
        const float* tg = targets + (size_t)b * NNV;
        const float* qb = qs + (size_t)b * NNV;
        const float* mb = means + (size_t)b * NNV;
#pragma unroll 4
        for (int i = 0; i < NNV / 256; ++i) {
            int n = t + i * 256;
            float tv = tg[n], q = qb[n], mu = mb[n], ps = psi[n];
            float w, wd;
            if (tv >= rho_s) {
                float y = __logf(tv);
                w = 1.0f / ps;
                float d = y - mu;
                wd = w * d;
                s_wdd += wd * d;
                s_nb += 1.0f;
                s_mlp += __logf(ps);
                s_extra += __logf(q) - y;
            } else {
                w = 0.f; wd = 0.f;
                s_uni += __logf(1.0f - q) - lrho;
            }
            wbuf[n] = w;
            wdbuf[n] = wd;
        }
    }
    // block-reduce the 5 scalars
#pragma unroll
    for (int off = 32; off > 0; off >>= 1) {
        s_uni  += __shfl_down(s_uni, off);
        s_wdd  += __shfl_down(s_wdd, off);
        s_nb   += __shfl_down(s_nb, off);
        s_mlp  += __shfl_down(s_mlp, off);
        s_extra+= __shfl_down(s_extra, off);
    }
    if (lane == 0) {
        sred[wid * 5 + 0] = s_uni;
        sred[wid * 5 + 1] = s_wdd;
        sred[wid * 5 + 2] = s_nb;
        sred[wid * 5 + 3] = s_mlp;
        sred[wid * 5 + 4] = s_extra;
    }

    // ---------- phase 2: A = sum_n w C C^T (4x4 per thread), u alongside ----------
    const int cg = t & 15;        // column group
    const int rg = t >> 4;        // row group
    const int rowbase = rg * 4;
    const int colbase = cg * 4;

    float a00=0,a01=0,a02=0,a03=0, a10=0,a11=0,a12=0,a13=0;
    float a20=0,a21=0,a22=0,a23=0, a30=0,a31=0,a32=0,a33=0;
    float u0=0,u1=0,u2=0,u3=0;

    for (int n0 = 0; n0 < NNV; n0 += TILE) {
        __syncthreads();  // previous tile consumed (and phase-1 writes visible on first pass)
        {   // stage Ct[n0..n0+31][0..63] into Cs (stride 68), float4 per thread, 2 iters
            const int k4 = (t & 15) * 4;
            const int nnb = t >> 4;
#pragma unroll
            for (int i = 0; i < 2; ++i) {
                int nn = nnb + i * 16;
                float4 v = *(const float4*)(Ct + (size_t)(n0 + nn) * 64 + k4);
                *(float4*)(AC + nn * 68 + k4) = v;
            }
        }
        __syncthreads();
#pragma unroll 4
        for (int nn = 0; nn < TILE; ++nn) {
            float w  = wbuf[n0 + nn];    // broadcast
            float wd = wdbuf[n0 + nn];   // broadcast
            const float4 cr = *(const float4*)(AC + nn * 68 + rowbase);
            const float4 cc = *(const float4*)(AC + nn * 68 + colbase);
            float c0 = cr.x * w, c1 = cr.y * w, c2 = cr.z * w, c3 = cr.w * w;
            a00 += c0 * cc.x; a01 += c0 * cc.y; a02 += c0 * cc.z; a03 += c0 * cc.w;
            a10 += c1 * cc.x; a11 += c1 * cc.y; a12 += c1 * cc.z; a13 += c1 * cc.w;
            a20 += c2 * cc.x; a21 += c2 * cc.y; a22 += c2 * cc.z; a23 += c2 * cc.w;
            a30 += c3 * cc.x; a31 += c3 * cc.y; a32 += c3 * cc.z; a33 += c3 * cc.w;
            u0 += wd * cc.x; u1 += wd * cc.y; u2 += wd * cc.z; u3 += wd * cc.w;
        }
    }

    // ---------- phase 3: write A (+I) to LDS (stride 65), Cholesky, solve ----------
    __syncthreads();  // everyone done reading Cs before overwrite
    {
        float av[16] = {a00,a01,a02,a03,a10,a11,a12,a13,a20,a21,a22,a23,a30,a31,a32,a33};
#pragma unroll
        for (int i = 0; i < 4; ++i) {
#pragma unroll
            for (int j = 0; j < 4; ++j) {
                int r = rowbase + i, c = colbase + j;
                float v = av[i * 4 + j];
                if (r == c) v += 1.0f;
                AC[r * 65 + c] = v;
            }
        }
        if (t < 16) {   // rg==0 threads hold the full u for their 4 columns
            ubuf[colbase + 0] = u0;
            ubuf[colbase + 1] = u1;
            ubuf[colbase + 2] = u2;
            ubuf[colbase + 3] = u3;
        }
    }
    __syncthreads();

    // right-looking Cholesky, full-square trailing update; L lands in lower triangle
    float logdetA = 0.f;
    for (int j = 0; j < 64; ++j) {
        float Ajj = AC[j * 65 + j];
        float invs = 1.0f / sqrtf(Ajj);
        logdetA += __logf(Ajj);              // 2*log(Ljj) = log(Ajj)
        if (t > j && t < 64) {
            float c = AC[t * 65 + j] * invs;
            AC[t * 65 + j] = c;
            colv[t] = c;
        }
        if (t == j) AC[j * 65 + j] = Ajj * invs;   // sqrt(Ajj)
        __syncthreads();
        if (lane > j) {
            float cl = colv[lane];
#pragma unroll
            for (int m = 0; m < 16; ++m) {
                int i = m * 4 + wid;               // wave-uniform row index
                if (i > j) AC[i * 65 + lane] -= colv[i] * cl;
            }
        }
        __syncthreads();
    }

    // forward solve L z = u ; z2 = ||z||^2 (computed uniformly by all threads)
    float z2 = 0.f;
    for (int j = 0; j < 64; ++j) {
        float zj = ubuf[j] / AC[j * 65 + j];
        z2 += zj * zj;
        if (t > j && t < 64) ubuf[t] -= AC[t * 65 + j] * zj;
        __syncthreads();
    }

    // ---------- final assembly ----------
    if (t == 0) {
        float uni = 0.f, wdd = 0.f, nb = 0.f, mlp = 0.f, extra = 0.f;
#pragma unroll
        for (int w = 0; w < 4; ++w) {
            uni  += sred[w * 5 + 0];
            wdd  += sred[w * 5 + 1];
            nb   += sred[w * 5 + 2];
            mlp  += sred[w * 5 + 3];
            extra+= sred[w * 5 + 4];
        }
        const float LOG2PI = 1.8378770664093453f;
        float quad = wdd - z2;
        float gauss = -0.5f * (nb * LOG2PI + mlp + logdetA + quad);
        out[b] = uni + gauss + extra;
    }
}

extern "C" void kernel_launch(void* const* d_in, const int* in_sizes, int n_in,
                              void* d_out, int out_size, void* d_ws, size_t ws_size,
                              hipStream_t stream) {
    const float* targets = (const float*)d_in[0];
    const float* rho     = (const float*)d_in[1];
    const float* qs      = (const float*)d_in[2];
    const float* means   = (const float*)d_in[3];
    const float* C       = (const float*)d_in[4];
    const float* psi     = (const float*)d_in[5];
    float* out = (float*)d_out;
    float* Ct  = (float*)d_ws;   // NNV*KKV floats = 1 MB

    ct_transpose<<<NNV / 64, 256, 0, stream>>>(C, Ct);
    zif_main<<<BBV, 256, 0, stream>>>(targets, rho, qs, means, Ct, psi, out);
}

// Round 2
// 99.602 us; speedup vs baseline: 3.5939x; 3.5939x over previous
//
#include <hip/hip_runtime.h>
#include <math.h>

#define NNV 4096   // N
#define KKV 64     // K
#define BBV 256    // B
#define CHN 256    // n-chunk staged in LDS
#define NCH (NNV / CHN)

typedef unsigned short u16;
typedef unsigned int u32;
typedef u32  u32x4  __attribute__((ext_vector_type(4)));
typedef short bf16x8 __attribute__((ext_vector_type(8)));
typedef float f32x4  __attribute__((ext_vector_type(4)));
typedef float f32x16 __attribute__((ext_vector_type(16)));

__device__ inline u16 f2bf(float x) {           // RNE f32 -> bf16
    u32 u = __float_as_uint(x);
    u = u + 0x7FFFu + ((u >> 16) & 1u);
    return (u16)(u >> 16);
}

// ================= K1: elementwise prep (+ Cs build in blocks 256..319) ===========
__global__ __launch_bounds__(256) void prep(
    const float* __restrict__ targets, const float* __restrict__ rho,
    const float* __restrict__ qs, const float* __restrict__ means,
    const float* __restrict__ C, const float* __restrict__ psi,
    u16* __restrict__ Csbf, u16* __restrict__ dsbf,
    u32* __restrict__ mask2, float* __restrict__ scal) {
    const int blk = blockIdx.x;
    const int t = threadIdx.x;

    if (blk >= BBV) {                    // Cs = C * rsqrt(psi), bf16, row-major [64][4096]
        const int k = blk - BBV;
        const float* Crow = C + (size_t)k * NNV;
        u16* Orow = Csbf + (size_t)k * NNV;
        const int base = t * 16;
#pragma unroll
        for (int j = 0; j < 16; j += 4) {
            float4 cv = *(const float4*)(Crow + base + j);
            float4 pv = *(const float4*)(psi + base + j);
            u32 w0 = (u32)f2bf(cv.x * rsqrtf(pv.x)) | ((u32)f2bf(cv.y * rsqrtf(pv.y)) << 16);
            u32 w1 = (u32)f2bf(cv.z * rsqrtf(pv.z)) | ((u32)f2bf(cv.w * rsqrtf(pv.w)) << 16);
            *(uint2*)(Orow + base + j) = make_uint2(w0, w1);
        }
        return;
    }

    __shared__ float sred[4][5];
    const int b = blk;
    const int lane = t & 63, wid = t >> 6;
    const float rho_s = rho[0];
    const float lrho = __logf(rho_s);
    const int base = t * 16;
    const float* tg = targets + (size_t)b * NNV + base;
    const float* qb = qs + (size_t)b * NNV + base;
    const float* mb = means + (size_t)b * NNV + base;
    const float* pb = psi + base;

    float tvv[16], qv[16], muv[16], pv[16];
#pragma unroll
    for (int j = 0; j < 16; j += 4) {
        *(float4*)(tvv + j) = *(const float4*)(tg + j);
        *(float4*)(qv + j)  = *(const float4*)(qb + j);
        *(float4*)(muv + j) = *(const float4*)(mb + j);
        *(float4*)(pv + j)  = *(const float4*)(pb + j);
    }

    float s_uni = 0.f, s_wdd = 0.f, s_nb = 0.f, s_mlp = 0.f, s_extra = 0.f;
    u16 dsv[16]; bool mk[16];
#pragma unroll
    for (int j = 0; j < 16; ++j) {
        bool m = tvv[j] >= rho_s;
        float ds = 0.f;
        if (m) {
            float y = __logf(tvv[j]);
            float d = y - muv[j];
            ds = d * rsqrtf(pv[j]);               // ds^2 = w*d^2
            s_wdd += ds * ds;
            s_nb += 1.f;
            s_mlp += __logf(pv[j]);
            s_extra += __logf(qv[j]) - y;
        } else {
            s_uni += __logf(1.f - qv[j]) - lrho;
        }
        dsv[j] = f2bf(ds);
        mk[j] = m;
    }
    u32 mw[8], dp[8];
#pragma unroll
    for (int i = 0; i < 8; ++i) {
        mw[i] = (mk[2*i] ? 0xFFFFu : 0u) | (mk[2*i+1] ? 0xFFFF0000u : 0u);
        dp[i] = (u32)dsv[2*i] | ((u32)dsv[2*i+1] << 16);
    }
    *(u32x4*)(dsbf + (size_t)b * NNV + base)     = ((u32x4*)dp)[0];
    *(u32x4*)(dsbf + (size_t)b * NNV + base + 8) = ((u32x4*)dp)[1];
    *(u32x4*)(mask2 + (size_t)b * (NNV/2) + t*8)     = ((u32x4*)mw)[0];
    *(u32x4*)(mask2 + (size_t)b * (NNV/2) + t*8 + 4) = ((u32x4*)mw)[1];

#pragma unroll
    for (int off = 32; off > 0; off >>= 1) {
        s_uni  += __shfl_down(s_uni, off);
        s_wdd  += __shfl_down(s_wdd, off);
        s_nb   += __shfl_down(s_nb, off);
        s_mlp  += __shfl_down(s_mlp, off);
        s_extra+= __shfl_down(s_extra, off);
    }
    if (lane == 0) {
        sred[wid][0] = s_uni; sred[wid][1] = s_wdd; sred[wid][2] = s_nb;
        sred[wid][3] = s_mlp; sred[wid][4] = s_extra;
    }
    __syncthreads();
    if (t == 0) {
        float a0=0,a1=0,a2=0,a3=0,a4=0;
#pragma unroll
        for (int w4 = 0; w4 < 4; ++w4) {
            a0 += sred[w4][0]; a1 += sred[w4][1]; a2 += sred[w4][2];
            a3 += sred[w4][3]; a4 += sred[w4][4];
        }
        scal[b*5+0]=a0; scal[b*5+1]=a1; scal[b*5+2]=a2; scal[b*5+3]=a3; scal[b*5+4]=a4;
    }
}

// ================= K2: per-batch Gram via MFMA ===========
// G = [m ? Cs : 0 (64 rows); ds]; computes A00,A10,A11 (32x32 tiles) and u (row64).
__global__ __launch_bounds__(512) void gram(
    const u16* __restrict__ Csbf, const u16* __restrict__ dsbf,
    const u32* __restrict__ mask2g, float* __restrict__ Abuf, float* __restrict__ Uf) {
    __shared__ __align__(16) u16 gbuf[2][KKV * CHN];   // swizzled Cs chunk, 32 KB each
    __shared__ __align__(16) u16 dsrow[2][CHN];
    __shared__ __align__(16) u32 m2[NNV / 2];          // packed bf16-pair masks, 8 KB

    const int b = blockIdx.x;
    const int t = threadIdx.x;
    const int lane = t & 63;
    const int w = t >> 6;
    const int half = w & 1;
    const int tilid = w >> 1;          // 0,1,2 = A00,A10,A11 ; 3 = u-waves
    const int l31 = lane & 31;
    const int hsel = lane >> 5;

    {   // stage full-batch mask words
        u32x4 v = *(const u32x4*)(mask2g + (size_t)b * (NNV/2) + t*4);
        *(u32x4*)(m2 + t*4) = v;
    }

    f32x16 acc;
#pragma unroll
    for (int i = 0; i < 16; ++i) acc[i] = 0.f;
    f32x4 ua, ubv;
#pragma unroll
    for (int i = 0; i < 4; ++i) { ua[i] = 0.f; ubv[i] = 0.f; }

#define STAGE(cc, pp) do {                                                          \
    _Pragma("unroll")                                                               \
    for (int i_ = 0; i_ < 4; ++i_) {                                                \
        int beta0 = w*256 + i_*64;                                                  \
        int beta = beta0 + lane;                                                    \
        int r_ = beta >> 5, blkP = beta & 31;                                       \
        int blkS = blkP ^ (r_ & 15);   /* source pre-swizzle (m173 pattern) */      \
        const u16* src = Csbf + (size_t)r_ * NNV + (cc)*CHN + blkS*8;               \
        __builtin_amdgcn_global_load_lds(                                           \
            (const __attribute__((address_space(1))) void*)src,                     \
            (__attribute__((address_space(3))) void*)(&gbuf[pp][beta0*8]),          \
            16, 0, 0);                                                              \
    }                                                                               \
    if (w == 7 && lane < 32) {                                                      \
        u32x4 dv_ = *(const u32x4*)(dsbf + (size_t)b * NNV + (cc)*CHN + lane*8);    \
        *(u32x4*)(&dsrow[pp][lane*8]) = dv_;                                        \
    }                                                                               \
} while (0)

    STAGE(0, 0);
    __syncthreads();

    for (int c = 0; c < NCH; ++c) {
        const int p = c & 1;
        if (c + 1 < NCH) STAGE(c + 1, p ^ 1);
        const char* gb = (const char*)gbuf[p];
        if (w < 6) {
            const int rbA = (tilid == 0) ? 0 : 32;
            const int rbB = (tilid == 2) ? 32 : 0;
            const int rA = rbA + l31, rB = rbB + l31;
            const int swA = (rA & 15) << 4, swB = (rB & 15) << 4;
            const char* mbase = (const char*)m2 + c*512 + hsel*16;
#pragma unroll
            for (int s8 = 0; s8 < 8; ++s8) {
                const int s = half*8 + s8;
                const int colbyte = s*32 + hsel*16;
                u32x4 fB = *(const u32x4*)(gb + rB*512 + (colbyte ^ swB));
                u32x4 fA;
                if (tilid == 1) fA = *(const u32x4*)(gb + rA*512 + (colbyte ^ swA));
                else            fA = fB;                       // diag tiles: reuse read
                u32x4 mkv = *(const u32x4*)(mbase + s*32);     // broadcast per half-wave
                fA = fA & mkv;                                  // mask A-side only (m^2=m)
                acc = __builtin_amdgcn_mfma_f32_32x32x16_bf16(
                        __builtin_bit_cast(bf16x8, fA),
                        __builtin_bit_cast(bf16x8, fB), acc, 0, 0, 0);
            }
        } else {
            const int cb0 = (w == 6) ? 0 : 32;
            const int l15 = lane & 15;
            const int g4 = lane >> 4;
            const int r0 = cb0 + l15, r1 = r0 + 16;
            const int sw0 = (r0 & 15) << 4, sw1 = (r1 & 15) << 4;
            const char* dr = (const char*)dsrow[p];
#pragma unroll
            for (int su = 0; su < 8; ++su) {
                const int colbyte = su*64 + g4*16;
                u32x4 dv = *(const u32x4*)(dr + colbyte);      // broadcast
                if (l15 != 0) dv = dv ^ dv;                    // A rows 1..15 = 0
                u32x4 f0 = *(const u32x4*)(gb + r0*512 + (colbyte ^ sw0));
                u32x4 f1 = *(const u32x4*)(gb + r1*512 + (colbyte ^ sw1));
                ua  = __builtin_amdgcn_mfma_f32_16x16x32_bf16(
                        __builtin_bit_cast(bf16x8, dv), __builtin_bit_cast(bf16x8, f0), ua, 0,0,0);
                ubv = __builtin_amdgcn_mfma_f32_16x16x32_bf16(
                        __builtin_bit_cast(bf16x8, dv), __builtin_bit_cast(bf16x8, f1), ubv, 0,0,0);
            }
        }
        __syncthreads();
    }

    // epilogue: combine n-halves, write A tiles + u
    float* red = (float*)&gbuf[0][0];
    if (w < 6 && half == 0) {
#pragma unroll
        for (int g = 0; g < 16; ++g) {
            int row = (g & 3) + 8*(g >> 2) + 4*hsel;          // 32x32 C/D layout (m74/m101)
            red[tilid*1024 + row*32 + l31] = acc[g];
        }
    }
    if (w >= 6 && lane < 16) {                                 // 16x16 D row0 = u
        const int cb0 = (w == 6) ? 0 : 32;
        Uf[b*KKV + cb0 + lane]      = ua[0];
        Uf[b*KKV + cb0 + 16 + lane] = ubv[0];
    }
    __syncthreads();
    if (w < 6 && half == 1) {
#pragma unroll
        for (int g = 0; g < 16; ++g) {
            int row = (g & 3) + 8*(g >> 2) + 4*hsel;
            float v = red[tilid*1024 + row*32 + l31] + acc[g];
            int gr = (tilid == 0) ? row : 32 + row;
            int gc = (tilid == 2) ? 32 + l31 : l31;
            Abuf[(size_t)b*4096 + gr*64 + gc] = v;
        }
    }
#undef STAGE
}

// ================= K3: Cholesky + solve + assembly (round-1 validated path) ===========
__global__ __launch_bounds__(256) void chol_solve(
    const float* __restrict__ Abuf, const float* __restrict__ Uf,
    const float* __restrict__ scal, float* __restrict__ out) {
    __shared__ float AC[64 * 65];
    __shared__ float colv[64];
    __shared__ float ub[64];
    const int b = blockIdx.x;
    const int t = threadIdx.x;
    const int lane = t & 63, wid = t >> 6;

#pragma unroll
    for (int i = 0; i < 16; ++i) {
        int idx = i*256 + t;
        int r = idx >> 6, cc = idx & 63;
        float v = Abuf[(size_t)b*4096 + idx];     // upper-right 32x32 is unwritten garbage, never read
        AC[r*65 + cc] = v + ((r == cc) ? 1.f : 0.f);
    }
    if (t < 64) ub[t] = Uf[b*64 + t];
    __syncthreads();

    float logdetA = 0.f;
    for (int j = 0; j < 64; ++j) {
        float Ajj = AC[j*65 + j];
        float invs = 1.0f / sqrtf(Ajj);
        logdetA += __logf(Ajj);
        if (t > j && t < 64) {
            float cv_ = AC[t*65 + j] * invs;
            AC[t*65 + j] = cv_;
            colv[t] = cv_;
        }
        if (t == j) AC[j*65 + j] = Ajj * invs;
        __syncthreads();
        if (lane > j) {
            float cl = colv[lane];
#pragma unroll
            for (int m_ = 0; m_ < 16; ++m_) {
                int i2 = m_*4 + wid;
                if (i2 > j) AC[i2*65 + lane] -= colv[i2] * cl;
            }
        }
        __syncthreads();
    }

    float z2 = 0.f;
    for (int j = 0; j < 64; ++j) {
        float zj = ub[j] / AC[j*65 + j];
        z2 += zj * zj;
        if (t > j && t < 64) ub[t] -= AC[t*65 + j] * zj;
        __syncthreads();
    }

    if (t == 0) {
        float uni = scal[b*5+0], wdd = scal[b*5+1], nb = scal[b*5+2],
              mlp = scal[b*5+3], extra = scal[b*5+4];
        const float LOG2PI = 1.8378770664093453f;
        out[b] = uni + extra - 0.5f * (nb * LOG2PI + mlp + logdetA + (wdd - z2));
    }
}

extern "C" void kernel_launch(void* const* d_in, const int* in_sizes, int n_in,
                              void* d_out, int out_size, void* d_ws, size_t ws_size,
                              hipStream_t stream) {
    const float* targets = (const float*)d_in[0];
    const float* rho     = (const float*)d_in[1];
    const float* qs      = (const float*)d_in[2];
    const float* means   = (const float*)d_in[3];
    const float* C       = (const float*)d_in[4];
    const float* psi     = (const float*)d_in[5];
    float* out = (float*)d_out;

    char* ws = (char*)d_ws;
    u16* Csbf  = (u16*)(ws);                                      // 512 KB
    u16* dsbf  = (u16*)(ws + 0x80000);                            // 2 MB
    u32* mask2 = (u32*)(ws + 0x280000);                           // 2 MB
    float* Abuf = (float*)(ws + 0x480000);                        // 4 MB
    float* Uf   = (float*)(ws + 0x880000);                        // 64 KB
    float* scal = (float*)(ws + 0x890000);                        // 5 KB

    prep<<<BBV + KKV, 256, 0, stream>>>(targets, rho, qs, means, C, psi,
                                        Csbf, dsbf, mask2, scal);
    gram<<<BBV, 512, 0, stream>>>(Csbf, dsbf, mask2, Abuf, Uf);
    chol_solve<<<BBV, 256, 0, stream>>>(Abuf, Uf, scal, out);
}